// Round 16
// baseline (367.586 us; speedup 1.0000x reference)
//
#include <hip/hip_runtime.h>
#include <hip/hip_bf16.h>

#define BATCH   256
#define NLAYERS 32
#define HID     1024
#define INTER   2816
#define BK      64

typedef __attribute__((ext_vector_type(8))) short bf16x8;
typedef __attribute__((ext_vector_type(4))) float f32x4;
typedef __attribute__((ext_vector_type(4))) int   i32x4;

__device__ __forceinline__ ushort f2bf(float f) {
  __hip_bfloat16 b = __float2bfloat16(f);   // RNE
  return *reinterpret_cast<ushort*>(&b);
}

__device__ __forceinline__ bf16x8 cvt8(f32x4 a, f32x4 b) {
  bf16x8 o;
  o[0] = (short)f2bf(a[0]); o[1] = (short)f2bf(a[1]);
  o[2] = (short)f2bf(a[2]); o[3] = (short)f2bf(a[3]);
  o[4] = (short)f2bf(b[0]); o[5] = (short)f2bf(b[1]);
  o[6] = (short)f2bf(b[2]); o[7] = (short)f2bf(b[3]);
  return o;
}

// ---------------------------------------------------------------------------
// Kernel 0: pack h (B,N,D) fp32 -> Xp[n][b][d] bf16.  UNCHANGED (~10 us).
// ---------------------------------------------------------------------------
__global__ __launch_bounds__(256) void k_pack_g(
    const float* __restrict__ h, ushort* __restrict__ Xp) {
  const int r    = blockIdx.x * 4 + (threadIdx.x >> 6);   // 0..8191 = b*32+n
  const int lane = threadIdx.x & 63;
  const int ro   = ((r & 31) * 256 + (r >> 5)) * 1024;    // out row = n*256+b
  const float* src = h + (size_t)r * 1024 + lane * 4;
  ushort* dst      = Xp + ro + lane * 4;
#pragma unroll
  for (int g = 0; g < 4; ++g) {
    f32x4 v = *(const f32x4*)(src + g * 256);
    ushort4 o;
    o.x = f2bf(v[0]); o.y = f2bf(v[1]); o.z = f2bf(v[2]); o.w = f2bf(v[3]);
    *(ushort4*)(dst + g * 256) = o;
  }
}

// ---------------------------------------------------------------------------
// Kernel 1: act = silu(X Wg^T)*(X Wu^T).  R4's EXACT step structure (best
// measured: 1307 ns/block-step), but each block now runs FOUR consecutive
// 32-col i-tiles sequentially (sub-loop around the proven K-loop).
// Grid 2816 -> 704 blocks; per-block useful steps 16 -> 64, amortizing the
// inferred ~9 us/block fixed overhead (launch + cold-B prologue + fill/drain
// + epilogue).  Discriminating test of the per-block-overhead theory.
// Everything inside the K-loop is byte-identical to R4.
// ---------------------------------------------------------------------------
__global__ __launch_bounds__(512) void k_gateup_g(
    const ushort* __restrict__ Xp, const float* __restrict__ Wg,
    const float* __restrict__ Wu, ushort* __restrict__ act) {
  const int bid   = blockIdx.x;            // 0..703
  const int layer = bid / 22;              // 22 tile-groups of 4 per layer
  const int itg   = bid % 22;
  const int tid   = threadIdx.x;
  const int lane  = tid & 63;
  const int wave  = tid >> 6;
  const int m0    = wave * 32;             // wave-exclusive 32 batch rows

  __shared__ ushort lds[BATCH * BK + 64 * BK];   // 40 KiB
  ushort* Al = lds;
  ushort* Wl = lds + BATCH * BK;

  // A staging geometry (i-tile independent): 4 granules/thread
  int aldst[4];
  const ushort* asrc[4];
#pragma unroll
  for (int r = 0; r < 4; ++r) {
    int g = tid + 512 * r;
    int arow = g >> 3, akc = g & 7;
    aldst[r] = arow * BK + ((akc ^ (arow & 7)) << 3);
    asrc[r] = Xp + ((size_t)layer * BATCH + arow) * HID + akc * 8;
  }
  // B staging geometry: row tid>>3 (<32 Wg, >=32 Wu), slot tid&7
  const int wrow = tid >> 3, wsl = tid & 7;
  const int wldst = wrow * BK + ((wsl ^ (wrow & 7)) << 3);
  const float* wrowbase = (wrow < 32 ? Wg + (size_t)wrow * HID
                                     : Wu + (size_t)(wrow - 32) * HID) +
                          (size_t)layer * INTER * HID + wsl * 8;

  const int r16 = lane & 15;
  const int g4  = lane >> 4;
  const int r4  = g4 * 4;

  for (int sub = 0; sub < 4; ++sub) {
    const int i0 = (itg * 4 + sub) * 32;
    const float* wsrc = wrowbase + (size_t)i0 * HID;

    f32x4 acc[2][4] = {};                  // [m][n]; n 0..1 gate, 2..3 up

    i32x4 ra[4];
    f32x4 rw[2];
#pragma unroll
    for (int r = 0; r < 4; ++r) ra[r] = *(const i32x4*)asrc[r];
    rw[0] = *(const f32x4*)wsrc; rw[1] = *(const f32x4*)(wsrc + 4);

    const int NK = HID / BK;               // 16
    for (int k = 0; k < NK; ++k) {
      __syncthreads();
#pragma unroll
      for (int r = 0; r < 4; ++r) *(i32x4*)&Al[aldst[r]] = ra[r];
      *(bf16x8*)&Wl[wldst] = cvt8(rw[0], rw[1]);
      __syncthreads();

      if (k + 1 < NK) {                    // prefetch k+1 (in flight across MFMA)
        int off = (k + 1) * BK;
#pragma unroll
        for (int r = 0; r < 4; ++r) ra[r] = *(const i32x4*)(asrc[r] + off);
        rw[0] = *(const f32x4*)(wsrc + off); rw[1] = *(const f32x4*)(wsrc + off + 4);
      }

#pragma unroll
      for (int ks = 0; ks < 2; ++ks) {
        const int kg = ks * 4 + g4;
        bf16x8 af[2];
#pragma unroll
        for (int m = 0; m < 2; ++m) {
          int row = m0 + m * 16 + r16;
          af[m] = *(bf16x8*)&Al[row * BK + ((kg ^ (row & 7)) << 3)];
        }
#pragma unroll
        for (int n = 0; n < 4; ++n) {
          int row = n * 16 + r16;
          bf16x8 bw = *(bf16x8*)&Wl[row * BK + ((kg ^ (row & 7)) << 3)];
#pragma unroll
          for (int m = 0; m < 2; ++m)
            acc[m][n] = __builtin_amdgcn_mfma_f32_16x16x32_bf16(af[m], bw, acc[m][n], 0, 0, 0);
        }
      }
    }

    // epilogue: silu(gate)*up, thread-local.  C/D: col=lane&15, row=g4*4+r
#pragma unroll
    for (int m = 0; m < 2; ++m)
#pragma unroll
      for (int n = 0; n < 2; ++n)
#pragma unroll
        for (int r = 0; r < 4; ++r) {
          float g = acc[m][n][r];
          float u = acc[m][n + 2][r];
          float a = (g / (1.f + __expf(-g))) * u;
          int b = m0 + m * 16 + r4 + r;
          int i = i0 + n * 16 + r16;
          act[((size_t)layer * BATCH + b) * INTER + i] = f2bf(a);
        }
  }
}

// ---------------------------------------------------------------------------
// Kernel 2: out[b][layer][d] = act Wd^T.  UNCHANGED R1 structure (~65 us,
// at its roofline).
// ---------------------------------------------------------------------------
__global__ __launch_bounds__(512) void k_down_g(
    const ushort* __restrict__ act, const float* __restrict__ Wd,
    float* __restrict__ out) {
  const int bid   = blockIdx.x;
  const int layer = bid / (HID / 64);
  const int dtile = bid % (HID / 64);
  const int d0    = dtile * 64;
  const int tid   = threadIdx.x;
  const int lane  = tid & 63;
  const int wave  = tid >> 6;
  const int wm    = wave >> 1;
  const int wn    = wave & 1;

  __shared__ ushort lds[BATCH * BK + 64 * BK];       // 40 KiB
  ushort* Al = lds;
  ushort* Wl = lds + BATCH * BK;

  f32x4 acc[4][2] = {};

  int aldst[4];
  const ushort* asrc[4];
#pragma unroll
  for (int r = 0; r < 4; ++r) {
    int g = tid + 512 * r;
    int arow = g >> 3, akc = g & 7;
    aldst[r] = arow * BK + ((akc ^ (arow & 7)) << 3);
    asrc[r] = act + ((size_t)layer * BATCH + arow) * INTER + akc * 8;
  }
  const int wrow = tid >> 3, wkc = tid & 7;
  const int wldst = wrow * BK + ((wkc ^ (wrow & 7)) << 3);
  const float* wsrc = Wd + (size_t)layer * HID * INTER + (size_t)(d0 + wrow) * INTER + wkc * 8;

  i32x4 ra[4];
  f32x4 rw[2];

#pragma unroll
  for (int r = 0; r < 4; ++r) ra[r] = *(const i32x4*)asrc[r];
  rw[0] = *(const f32x4*)wsrc; rw[1] = *(const f32x4*)(wsrc + 4);

  const int NK = INTER / BK;   // 44
  for (int k = 0; k < NK; ++k) {
    __syncthreads();
#pragma unroll
    for (int r = 0; r < 4; ++r) *(i32x4*)&Al[aldst[r]] = ra[r];
    *(bf16x8*)&Wl[wldst] = cvt8(rw[0], rw[1]);
    __syncthreads();

    if (k + 1 < NK) {
      int off = (k + 1) * BK;
#pragma unroll
      for (int r = 0; r < 4; ++r) ra[r] = *(const i32x4*)(asrc[r] + off);
      rw[0] = *(const f32x4*)(wsrc + off); rw[1] = *(const f32x4*)(wsrc + off + 4);
    }

#pragma unroll
    for (int ks = 0; ks < 2; ++ks) {
      const int kg = ks * 4 + (lane >> 4);
      bf16x8 af[4];
#pragma unroll
      for (int m = 0; m < 4; ++m) {
        int row = wm * 64 + m * 16 + (lane & 15);
        af[m] = *(bf16x8*)&Al[row * BK + ((kg ^ (row & 7)) << 3)];
      }
#pragma unroll
      for (int n = 0; n < 2; ++n) {
        int row = wn * 32 + n * 16 + (lane & 15);
        bf16x8 bw = *(bf16x8*)&Wl[row * BK + ((kg ^ (row & 7)) << 3)];
#pragma unroll
        for (int m = 0; m < 4; ++m)
          acc[m][n] = __builtin_amdgcn_mfma_f32_16x16x32_bf16(af[m], bw, acc[m][n], 0, 0, 0);
      }
    }
  }

  const int c16 = lane & 15;
  const int r4  = (lane >> 4) * 4;
#pragma unroll
  for (int m = 0; m < 4; ++m)
#pragma unroll
    for (int n = 0; n < 2; ++n)
#pragma unroll
      for (int r = 0; r < 4; ++r) {
        int b = wm * 64 + m * 16 + r4 + r;
        int d = d0 + wn * 32 + n * 16 + c16;
        out[(size_t)b * (NLAYERS * HID) + (size_t)layer * HID + d] = acc[m][n][r];
      }
}

extern "C" void kernel_launch(void* const* d_in, const int* in_sizes, int n_in,
                              void* d_out, int out_size, void* d_ws, size_t ws_size,
                              hipStream_t stream) {
  const float* h  = (const float*)d_in[0];
  const float* Wg = (const float*)d_in[1];
  const float* Wu = (const float*)d_in[2];
  const float* Wd = (const float*)d_in[3];
  float* out  = (float*)d_out;
  ushort* act = (ushort*)d_ws;                                   // 46.1 MB
  ushort* Xp  = (ushort*)d_ws + (size_t)NLAYERS * BATCH * INTER; // +16.8 MB

  hipLaunchKernelGGL(k_pack_g, dim3(BATCH * NLAYERS / 4), dim3(256), 0, stream,
                     h, Xp);
  hipLaunchKernelGGL(k_gateup_g, dim3(NLAYERS * 22), dim3(512), 0, stream,
                     Xp, Wg, Wu, act);
  hipLaunchKernelGGL(k_down_g, dim3(NLAYERS * (HID / 64)), dim3(512), 0, stream,
                     act, Wd, out);
}

// Round 17
// 329.345 us; speedup vs baseline: 1.1161x; 1.1161x over previous
//
#include <hip/hip_runtime.h>
#include <hip/hip_bf16.h>

#define BATCH   256
#define NLAYERS 32
#define HID     1024
#define INTER   2816
#define BK      64

typedef __attribute__((ext_vector_type(8))) short bf16x8;
typedef __attribute__((ext_vector_type(4))) float f32x4;
typedef __attribute__((ext_vector_type(4))) int   i32x4;

__device__ __forceinline__ ushort f2bf(float f) {
  __hip_bfloat16 b = __float2bfloat16(f);   // RNE
  return *reinterpret_cast<ushort*>(&b);
}

__device__ __forceinline__ bf16x8 cvt8(f32x4 a, f32x4 b) {
  bf16x8 o;
  o[0] = (short)f2bf(a[0]); o[1] = (short)f2bf(a[1]);
  o[2] = (short)f2bf(a[2]); o[3] = (short)f2bf(a[3]);
  o[4] = (short)f2bf(b[0]); o[5] = (short)f2bf(b[1]);
  o[6] = (short)f2bf(b[2]); o[7] = (short)f2bf(b[3]);
  return o;
}

// ---------------------------------------------------------------------------
// Kernel 0: pack h (B,N,D) fp32 -> Xp[n][b][d] bf16 (contiguous per layer).
// Measured ~10 us.
// ---------------------------------------------------------------------------
__global__ __launch_bounds__(256) void k_pack_f(
    const float* __restrict__ h, ushort* __restrict__ Xp) {
  const int r    = blockIdx.x * 4 + (threadIdx.x >> 6);   // 0..8191 = b*32+n
  const int lane = threadIdx.x & 63;
  const int ro   = ((r & 31) * 256 + (r >> 5)) * 1024;    // out row = n*256+b
  const float* src = h + (size_t)r * 1024 + lane * 4;
  ushort* dst      = Xp + ro + lane * 4;
#pragma unroll
  for (int g = 0; g < 4; ++g) {
    f32x4 v = *(const f32x4*)(src + g * 256);
    ushort4 o;
    o.x = f2bf(v[0]); o.y = f2bf(v[1]); o.z = f2bf(v[2]); o.w = f2bf(v[3]);
    *(ushort4*)(dst + g * 256) = o;
  }
}

// ---------------------------------------------------------------------------
// Kernel 1: act[layer][b][i] = silu(X Wg^T) * (X Wu^T), bf16 -> ws.
// R4 EXACT — measured best of 9 structural variants (230 us):
// BM=256 (weights from HBM exactly once), BN=32, BK=64, 512 thr, 40 KB LDS,
// XOR swizzle (0 conflicts), 2 barriers/step, 1-deep reg prefetch, natural
// block order (2816 blocks = 11/CU, balanced).  Alternatives measured worse:
// BN=64 payload (+3%), gload_lds dbuf (+11%), counted-vmcnt raw-barrier
// pipeline (+13%), XCD swizzle (+11%), 4-tile fusion (+33%), A-in-reg and
// zero-barrier fragment designs (2-3x).  B-tile = 64 rows (0..31 Wg,
// 32..63 Wu); waves 8M x 1N; silu fused thread-locally in the epilogue.
// ---------------------------------------------------------------------------
__global__ __launch_bounds__(512) void k_gateup_f(
    const ushort* __restrict__ Xp, const float* __restrict__ Wg,
    const float* __restrict__ Wu, ushort* __restrict__ act) {
  const int bid   = blockIdx.x;
  const int layer = bid / (INTER / 32);    // 88 itiles/layer
  const int it    = bid % (INTER / 32);
  const int i0    = it * 32;
  const int tid   = threadIdx.x;
  const int lane  = tid & 63;
  const int wave  = tid >> 6;
  const int m0    = wave * 32;             // wave-exclusive 32 batch rows

  __shared__ ushort lds[BATCH * BK + 64 * BK];   // 40 KiB
  ushort* Al = lds;
  ushort* Wl = lds + BATCH * BK;

  f32x4 acc[2][4] = {};                    // [m][n]; n 0..1 gate, 2..3 up

  // A staging: 2048 granules of 8 bf16; 4 per thread (i32x4 copy, no cvt)
  int aldst[4];
  const ushort* asrc[4];
#pragma unroll
  for (int r = 0; r < 4; ++r) {
    int g = tid + 512 * r;
    int arow = g >> 3, akc = g & 7;
    aldst[r] = arow * BK + ((akc ^ (arow & 7)) << 3);
    asrc[r] = Xp + ((size_t)layer * BATCH + arow) * HID + akc * 8;
  }
  // B staging: row tid>>3 (0..63: <32 -> Wg, >=32 -> Wu), 8 floats at (tid&7)*8
  const int wrow = tid >> 3, wsl = tid & 7;
  const int wldst = wrow * BK + ((wsl ^ (wrow & 7)) << 3);
  const float* wsrc = (wrow < 32 ? Wg + (size_t)(i0 + wrow) * HID
                                 : Wu + (size_t)(i0 + wrow - 32) * HID) +
                      (size_t)layer * INTER * HID + wsl * 8;

  i32x4 ra[4];
  f32x4 rw[2];
#pragma unroll
  for (int r = 0; r < 4; ++r) ra[r] = *(const i32x4*)asrc[r];
  rw[0] = *(const f32x4*)wsrc; rw[1] = *(const f32x4*)(wsrc + 4);

  const int r16 = lane & 15;
  const int g4  = lane >> 4;

  const int NK = HID / BK;                 // 16
  for (int k = 0; k < NK; ++k) {
    __syncthreads();
#pragma unroll
    for (int r = 0; r < 4; ++r) *(i32x4*)&Al[aldst[r]] = ra[r];
    *(bf16x8*)&Wl[wldst] = cvt8(rw[0], rw[1]);
    __syncthreads();

    if (k + 1 < NK) {                      // prefetch t+1 (in flight across MFMA)
      int off = (k + 1) * BK;
#pragma unroll
      for (int r = 0; r < 4; ++r) ra[r] = *(const i32x4*)(asrc[r] + off);
      rw[0] = *(const f32x4*)(wsrc + off); rw[1] = *(const f32x4*)(wsrc + off + 4);
    }

#pragma unroll
    for (int ks = 0; ks < 2; ++ks) {
      const int kg = ks * 4 + g4;
      bf16x8 af[2];
#pragma unroll
      for (int m = 0; m < 2; ++m) {
        int row = m0 + m * 16 + r16;
        af[m] = *(bf16x8*)&Al[row * BK + ((kg ^ (row & 7)) << 3)];
      }
#pragma unroll
      for (int n = 0; n < 4; ++n) {
        int row = n * 16 + r16;
        bf16x8 bw = *(bf16x8*)&Wl[row * BK + ((kg ^ (row & 7)) << 3)];
#pragma unroll
        for (int m = 0; m < 2; ++m)
          acc[m][n] = __builtin_amdgcn_mfma_f32_16x16x32_bf16(af[m], bw, acc[m][n], 0, 0, 0);
      }
    }
  }

  // epilogue: silu(gate)*up, thread-local.  C/D: col=lane&15, row=(lane>>4)*4+r
  const int r4 = (lane >> 4) * 4;
#pragma unroll
  for (int m = 0; m < 2; ++m)
#pragma unroll
    for (int n = 0; n < 2; ++n)
#pragma unroll
      for (int r = 0; r < 4; ++r) {
        float g = acc[m][n][r];
        float u = acc[m][n + 2][r];
        float a = (g / (1.f + __expf(-g))) * u;
        int b = m0 + m * 16 + r4 + r;
        int i = i0 + n * 16 + r16;
        act[((size_t)layer * BATCH + b) * INTER + i] = f2bf(a);
      }
}

// ---------------------------------------------------------------------------
// Kernel 2: out[b][layer][d] = act Wd^T.  R1 exact structure, natural block
// order.  Measured ~65 us (at its HBM roofline: Wd 369 MB + out 32 MB).
// ---------------------------------------------------------------------------
__global__ __launch_bounds__(512) void k_down_f(
    const ushort* __restrict__ act, const float* __restrict__ Wd,
    float* __restrict__ out) {
  const int bid   = blockIdx.x;
  const int layer = bid / (HID / 64);
  const int dtile = bid % (HID / 64);
  const int d0    = dtile * 64;
  const int tid   = threadIdx.x;
  const int lane  = tid & 63;
  const int wave  = tid >> 6;
  const int wm    = wave >> 1;
  const int wn    = wave & 1;

  __shared__ ushort lds[BATCH * BK + 64 * BK];       // 40 KiB
  ushort* Al = lds;
  ushort* Wl = lds + BATCH * BK;

  f32x4 acc[4][2] = {};

  int aldst[4];
  const ushort* asrc[4];
#pragma unroll
  for (int r = 0; r < 4; ++r) {
    int g = tid + 512 * r;
    int arow = g >> 3, akc = g & 7;
    aldst[r] = arow * BK + ((akc ^ (arow & 7)) << 3);
    asrc[r] = act + ((size_t)layer * BATCH + arow) * INTER + akc * 8;
  }
  const int wrow = tid >> 3, wkc = tid & 7;
  const int wldst = wrow * BK + ((wkc ^ (wrow & 7)) << 3);
  const float* wsrc = Wd + (size_t)layer * HID * INTER + (size_t)(d0 + wrow) * INTER + wkc * 8;

  i32x4 ra[4];
  f32x4 rw[2];

#pragma unroll
  for (int r = 0; r < 4; ++r) ra[r] = *(const i32x4*)asrc[r];
  rw[0] = *(const f32x4*)wsrc; rw[1] = *(const f32x4*)(wsrc + 4);

  const int NK = INTER / BK;   // 44
  for (int k = 0; k < NK; ++k) {
    __syncthreads();
#pragma unroll
    for (int r = 0; r < 4; ++r) *(i32x4*)&Al[aldst[r]] = ra[r];
    *(bf16x8*)&Wl[wldst] = cvt8(rw[0], rw[1]);
    __syncthreads();

    if (k + 1 < NK) {
      int off = (k + 1) * BK;
#pragma unroll
      for (int r = 0; r < 4; ++r) ra[r] = *(const i32x4*)(asrc[r] + off);
      rw[0] = *(const f32x4*)(wsrc + off); rw[1] = *(const f32x4*)(wsrc + off + 4);
    }

#pragma unroll
    for (int ks = 0; ks < 2; ++ks) {
      const int kg = ks * 4 + (lane >> 4);
      bf16x8 af[4];
#pragma unroll
      for (int m = 0; m < 4; ++m) {
        int row = wm * 64 + m * 16 + (lane & 15);
        af[m] = *(bf16x8*)&Al[row * BK + ((kg ^ (row & 7)) << 3)];
      }
#pragma unroll
      for (int n = 0; n < 2; ++n) {
        int row = wn * 32 + n * 16 + (lane & 15);
        bf16x8 bw = *(bf16x8*)&Wl[row * BK + ((kg ^ (row & 7)) << 3)];
#pragma unroll
        for (int m = 0; m < 4; ++m)
          acc[m][n] = __builtin_amdgcn_mfma_f32_16x16x32_bf16(af[m], bw, acc[m][n], 0, 0, 0);
      }
    }
  }

  const int c16 = lane & 15;
  const int r4  = (lane >> 4) * 4;
#pragma unroll
  for (int m = 0; m < 4; ++m)
#pragma unroll
    for (int n = 0; n < 2; ++n)
#pragma unroll
      for (int r = 0; r < 4; ++r) {
        int b = wm * 64 + m * 16 + r4 + r;
        int d = d0 + wn * 32 + n * 16 + c16;
        out[(size_t)b * (NLAYERS * HID) + (size_t)layer * HID + d] = acc[m][n][r];
      }
}

extern "C" void kernel_launch(void* const* d_in, const int* in_sizes, int n_in,
                              void* d_out, int out_size, void* d_ws, size_t ws_size,
                              hipStream_t stream) {
  const float* h  = (const float*)d_in[0];
  const float* Wg = (const float*)d_in[1];
  const float* Wu = (const float*)d_in[2];
  const float* Wd = (const float*)d_in[3];
  float* out  = (float*)d_out;
  ushort* act = (ushort*)d_ws;                                   // 46.1 MB
  ushort* Xp  = (ushort*)d_ws + (size_t)NLAYERS * BATCH * INTER; // +16.8 MB

  hipLaunchKernelGGL(k_pack_f, dim3(BATCH * NLAYERS / 4), dim3(256), 0, stream,
                     h, Xp);
  hipLaunchKernelGGL(k_gateup_f, dim3(NLAYERS * (INTER / 32)), dim3(512), 0, stream,
                     Xp, Wg, Wu, act);
  hipLaunchKernelGGL(k_down_f, dim3(NLAYERS * (HID / 64)), dim3(512), 0, stream,
                     act, Wd, out);
}